// Round 1
// baseline (124.364 us; speedup 1.0000x reference)
//
#include <hip/hip_runtime.h>

#define B_SZ 16384
#define D_SZ 256
#define C_SZ 2000
#define C_PAD 2048
#define MARGIN_F 1.0f
#define NBLK 1024

typedef float floatx16 __attribute__((ext_vector_type(16)));
typedef int   intx8    __attribute__((ext_vector_type(8)));

__device__ inline void gld_lds16(const void* g, void* l) {
  __builtin_amdgcn_global_load_lds(
      (const __attribute__((address_space(1))) void*)g,
      (__attribute__((address_space(3))) void*)l, 16, 0, 0);
}

// fp8 frag-major layout (verified R11-R14):
//   chunk(tile32, ks, lane) -> 8 fp8 bytes at base + ((tile*16 + ks)*64 + lane)*8
//   lane holds M[tile*32 + (lane&31)][ks*16 + (lane>>5)*8 + j], j=0..7
// Equivalently: k-oct o = 2*ks + (lane>>5); byte addr = tile*8192 + o*256 + (lane&31)*8.
// For mfma_scale_f32_32x32x64_f8f6f4, lane needs k = ks64*64 + (lane>>5)*32 + 0..31,
// i.e. the 4 stored k-octs o = ks64*8 + (lane>>5)*4 + g, g=0..3 (same bytes, regrouped).

__device__ inline int2 pack8_fp8(const float* v) {
  int lo = __builtin_amdgcn_cvt_pk_fp8_f32(v[0], v[1], 0, false);
  lo = __builtin_amdgcn_cvt_pk_fp8_f32(v[2], v[3], lo, true);
  int hi = __builtin_amdgcn_cvt_pk_fp8_f32(v[4], v[5], 0, false);
  hi = __builtin_amdgcn_cvt_pk_fp8_f32(v[6], v[7], hi, true);
  return make_int2(lo, hi);
}
__device__ inline float rt_fp8(float x) {   // round-trip through fp8 e4m3
  int p = __builtin_amdgcn_cvt_pk_fp8_f32(x, x, 0, false);
  return __builtin_amdgcn_cvt_f32_fp8(p, 0);
}
__device__ inline void unpack4_fp8(int w, float* o) {  // literal selectors only
  o[0] = __builtin_amdgcn_cvt_f32_fp8(w, 0);
  o[1] = __builtin_amdgcn_cvt_f32_fp8(w, 1);
  o[2] = __builtin_amdgcn_cvt_f32_fp8(w, 2);
  o[3] = __builtin_amdgcn_cvt_f32_fp8(w, 3);
}

// ---- kernel 1: sig (D x C) fp32 -> sigq frag-major fp8; zero out[0] ----
__global__ __launch_bounds__(256) void sigq_kernel(
    const float* __restrict__ sig, char* __restrict__ sigq,
    float* __restrict__ out) {
  int t = blockIdx.x * 256 + threadIdx.x;   // 65536 chunks of 8 B
  if (t == 0) out[0] = 0.f;
  int ln = t & 63, ks = (t >> 6) & 15, ct = t >> 10;
  int col = ct * 32 + (ln & 31);
  int kb = ks * 16 + (ln >> 5) * 8;
  float v[8];
#pragma unroll
  for (int j = 0; j < 8; j++)
    v[j] = (col < C_SZ) ? sig[(size_t)(kb + j) * C_SZ + col] : 0.f;
  *(int2*)(sigq + (size_t)t * 8) = pack8_fp8(v);
}

// ---- kernel 2: prep — unchanged (verified) ----
__global__ __launch_bounds__(256) void prep_kernel(
    const float* __restrict__ pred, const char* __restrict__ sigq,
    const int* __restrict__ label, char* __restrict__ predq,
    float* __restrict__ gt) {
  __shared__ float ldsP[16][260];
  int bid = (int)blockIdx.x;
  int tid = threadIdx.x;
  int lane = tid & 63;
  int w = tid >> 6;
  int tile = bid >> 1;
  int rhi = (bid & 1) * 16;
#pragma unroll
  for (int it = 0; it < 4; it++) {
    int idx = it * 1024 + tid * 4;
    int r = idx >> 8, c = idx & 255;
    *(float4*)&ldsP[r][c] = *(const float4*)(pred + (size_t)(bid * 16 + r) * D_SZ + c);
  }
  __syncthreads();
#pragma unroll
  for (int it = 0; it < 2; it++) {
    int ch = it * 256 + tid;
    int ri = ch & 15;
    int ks = (ch >> 4) & 15;
    int khh = ch >> 8;
    int kb = ks * 16 + khh * 8;
    int ln = khh * 32 + rhi + ri;
    float v[8];
#pragma unroll
    for (int j = 0; j < 8; j++) v[j] = ldsP[ri][kb + j];
    *(int2*)(predq + ((size_t)(tile * 16 + ks) * 64 + ln) * 8) = pack8_fp8(v);
  }
  int l = lane & 31;
  int half = lane >> 5;
#pragma unroll
  for (int it = 0; it < 2; it++) {
    int r = w * 4 + it * 2 + half;
    int row = bid * 16 + r;
    int lbl = label[row];
    int ltile = lbl >> 5, l5 = lbl & 31;
    int ks = l >> 1, khh = l & 1;
    int2 p8 = *(const int2*)(sigq +
        (((size_t)(ltile * 16 + ks) * 64) + khh * 32 + l5) * 8);
    float sv[8];
    unpack4_fp8(p8.x, sv);
    unpack4_fp8(p8.y, sv + 4);
    float s = 0.f;
#pragma unroll
    for (int j = 0; j < 8; j++)
      s += rt_fp8(ldsP[r][l * 8 + j]) * sv[j];
#pragma unroll
    for (int off = 16; off > 0; off >>= 1) s += __shfl_down(s, off, 32);
    if (l == 0) gt[row] = s;
  }
}

// ---- kernel 3: GEMM + hinge via MX-scaled fp8 (32x32x64, unit scales) ----
// block = 256 rows x 128 cols, 4 waves; wave = 64 rows (2 rowtiles) x 128.
// Same bytes/layout as the verified x16 path, regrouped 4 k-octs per operand.
// gt slice staged to LDS (1 KB) -> frees 32 VGPRs -> 4 blocks/CU, no tail.
__global__ __launch_bounds__(256, 4) void mfma_fused_kernel(
    const char* __restrict__ predq, const char* __restrict__ sigq,
    const float* __restrict__ gt, float* __restrict__ out) {
  __shared__ char Bs[4096 * 8];   // 32 KB
  __shared__ float gtl[256];      // 1 KB: gt for this block's 256 rows
  __shared__ float red[4];
  int tid = threadIdx.x;
  int lane = tid & 63;
  int w = tid >> 6;
  int kh = lane >> 5, lm = lane & 31;
  int bid = (int)blockIdx.x;
  int i = bid >> 3;
  int rsb = (bid & 7) * 8 + (i & 7);   // row superblock 0..63 (256 rows)
  int cg = i >> 3;                     // colgroup 0..15 (128 cols)

  // stage B tile (128 cols x 256 K fp8 = 32 KB), straight frag-major copy
#pragma unroll
  for (int s = 0; s < 8; s++) {
    int q0 = s * 256 + w * 64;         // 16 B chunk id, 0..2047
    gld_lds16(sigq + ((size_t)cg * 2048 + q0 + lane) * 16, (void*)(Bs + (size_t)q0 * 16));
  }
  // stage gt slice: 256 floats = 64 lanes x 16 B, wave 0 only
  if (w == 0)
    gld_lds16((const char*)gt + (size_t)rsb * 1024 + (size_t)lane * 16, (void*)gtl);

  // A frags: full K for 2 rowtiles as 4 x64-operands each (64 VGPR total)
  union frag8 { long l[4]; intx8 v; };
  frag8 a8[2][4];
#pragma unroll
  for (int rt = 0; rt < 2; rt++) {
    const char* abase = predq + (size_t)(rsb * 8 + w * 2 + rt) * 8192
                              + (size_t)(kh * 1024 + lm * 8);
#pragma unroll
    for (int ks = 0; ks < 4; ks++)
#pragma unroll
      for (int g = 0; g < 4; g++)
        a8[rt][ks].l[g] = *(const long*)(abase + ks * 2048 + g * 256);
  }
  __syncthreads();

  volatile const float* vgt = gtl;   // volatile: keep gt reads in LDS, not VGPRs
  float sum = 0.f;
#pragma unroll
  for (int ct = 0; ct < 4; ct++) {
    floatx16 acc0 = {}, acc1 = {};
    const char* bbase = Bs + ct * 8192 + kh * 1024 + lm * 8;
#pragma unroll
    for (int ks = 0; ks < 4; ks++) {
      frag8 b8;
#pragma unroll
      for (int g = 0; g < 4; g++)
        b8.l[g] = *(const long*)(bbase + ks * 2048 + g * 256);
      // unit scales: E8M0 127 -> 2^0; cbsz=0/blgp=0 -> fp8 e4m3 A and B
      acc0 = __builtin_amdgcn_mfma_scale_f32_32x32x64_f8f6f4(
          a8[0][ks].v, b8.v, acc0, 0, 0, 0, 127, 0, 127);
      acc1 = __builtin_amdgcn_mfma_scale_f32_32x32x64_f8f6f4(
          a8[1][ks].v, b8.v, acc1, 0, 0, 0, 127, 0, 127);
    }
    int col = cg * 128 + ct * 32 + lm;
    float keep = (col < C_SZ) ? 1.f : 0.f;   // padded cols: s=0 but hinge!=0
#pragma unroll
    for (int reg = 0; reg < 16; reg++) {
      int rl = (reg & 3) + 8 * (reg >> 2) + 4 * kh;  // C/D row map (verified R3)
      float mg0 = MARGIN_F - vgt[w * 64 + rl];
      float mg1 = MARGIN_F - vgt[w * 64 + 32 + rl];
      sum += keep * fmaxf(acc0[reg] + mg0, 0.f);
      sum += keep * fmaxf(acc1[reg] + mg1, 0.f);
    }
  }
#pragma unroll
  for (int off = 32; off > 0; off >>= 1) sum += __shfl_down(sum, off, 64);
  if (lane == 0) red[w] = sum;
  __syncthreads();
  // per-block share of the label-column constant: B_SZ*MARGIN / NBLK = 16
  if (tid == 0)
    atomicAdd(out, red[0] + red[1] + red[2] + red[3]
                   - (float)B_SZ * MARGIN_F / (float)NBLK);
}

extern "C" void kernel_launch(void* const* d_in, const int* in_sizes, int n_in,
                              void* d_out, int out_size, void* d_ws, size_t ws_size,
                              hipStream_t stream) {
  const float* pred  = (const float*)d_in[0];   // (B, D) fp32
  const int*   label = (const int*)d_in[1];     // (B,)
  // d_in[2] = train_classes = arange(C), unused
  const float* sig   = (const float*)d_in[3];   // (D, C) fp32
  float* out = (float*)d_out;

  float* gt    = (float*)d_ws;                                   // 64 KB
  char*  predq = (char*)d_ws + (128 << 10);                      // 4 MB
  char*  sigq  = (char*)d_ws + (128 << 10) + (4 << 20);          // 512 KB

  sigq_kernel<<<256, 256, 0, stream>>>(sig, sigq, out);
  prep_kernel<<<1024, 256, 0, stream>>>(pred, sigq, label, predq, gt);
  mfma_fused_kernel<<<NBLK, 256, 0, stream>>>(predq, sigq, gt, out);
}

// Round 2
// 110.801 us; speedup vs baseline: 1.1224x; 1.1224x over previous
//
#include <hip/hip_runtime.h>

#define B_SZ 16384
#define D_SZ 256
#define C_SZ 2000
#define C_PAD 2048
#define MARGIN_F 1.0f
#define NBLK 1024

typedef float floatx16 __attribute__((ext_vector_type(16)));
typedef int   intx8    __attribute__((ext_vector_type(8)));

__device__ inline void gld_lds16(const void* g, void* l) {
  __builtin_amdgcn_global_load_lds(
      (const __attribute__((address_space(1))) void*)g,
      (__attribute__((address_space(3))) void*)l, 16, 0, 0);
}

// fp8 frag-major layout (verified R11-R14):
//   chunk(tile32, ks, lane) -> 8 fp8 bytes at base + ((tile*16 + ks)*64 + lane)*8
//   lane holds M[tile*32 + (lane&31)][ks*16 + (lane>>5)*8 + j], j=0..7
// Equivalently: k-oct o = 2*ks + (lane>>5); byte addr = tile*8192 + o*256 + (lane&31)*8.
// For mfma_scale_f32_32x32x64_f8f6f4, lane needs k = ks64*64 + (lane>>5)*32 + 0..31,
// i.e. the 4 stored k-octs o = ks64*8 + (lane>>5)*4 + g, g=0..3 (same bytes, regrouped).
// Verified on HW in R1 (absmax = 0.0); R1's regression was register spill, not math.

__device__ inline int2 pack8_fp8(const float* v) {
  int lo = __builtin_amdgcn_cvt_pk_fp8_f32(v[0], v[1], 0, false);
  lo = __builtin_amdgcn_cvt_pk_fp8_f32(v[2], v[3], lo, true);
  int hi = __builtin_amdgcn_cvt_pk_fp8_f32(v[4], v[5], 0, false);
  hi = __builtin_amdgcn_cvt_pk_fp8_f32(v[6], v[7], hi, true);
  return make_int2(lo, hi);
}
__device__ inline float rt_fp8(float x) {   // round-trip through fp8 e4m3
  int p = __builtin_amdgcn_cvt_pk_fp8_f32(x, x, 0, false);
  return __builtin_amdgcn_cvt_f32_fp8(p, 0);
}
__device__ inline void unpack4_fp8(int w, float* o) {  // literal selectors only
  o[0] = __builtin_amdgcn_cvt_f32_fp8(w, 0);
  o[1] = __builtin_amdgcn_cvt_f32_fp8(w, 1);
  o[2] = __builtin_amdgcn_cvt_f32_fp8(w, 2);
  o[3] = __builtin_amdgcn_cvt_f32_fp8(w, 3);
}

// ---- kernel 1: sig (D x C) fp32 -> sigq frag-major fp8; zero out[0] ----
__global__ __launch_bounds__(256) void sigq_kernel(
    const float* __restrict__ sig, char* __restrict__ sigq,
    float* __restrict__ out) {
  int t = blockIdx.x * 256 + threadIdx.x;   // 65536 chunks of 8 B
  if (t == 0) out[0] = 0.f;
  int ln = t & 63, ks = (t >> 6) & 15, ct = t >> 10;
  int col = ct * 32 + (ln & 31);
  int kb = ks * 16 + (ln >> 5) * 8;
  float v[8];
#pragma unroll
  for (int j = 0; j < 8; j++)
    v[j] = (col < C_SZ) ? sig[(size_t)(kb + j) * C_SZ + col] : 0.f;
  *(int2*)(sigq + (size_t)t * 8) = pack8_fp8(v);
}

// ---- kernel 2: prep — unchanged (verified) ----
__global__ __launch_bounds__(256) void prep_kernel(
    const float* __restrict__ pred, const char* __restrict__ sigq,
    const int* __restrict__ label, char* __restrict__ predq,
    float* __restrict__ gt) {
  __shared__ float ldsP[16][260];
  int bid = (int)blockIdx.x;
  int tid = threadIdx.x;
  int lane = tid & 63;
  int w = tid >> 6;
  int tile = bid >> 1;
  int rhi = (bid & 1) * 16;
#pragma unroll
  for (int it = 0; it < 4; it++) {
    int idx = it * 1024 + tid * 4;
    int r = idx >> 8, c = idx & 255;
    *(float4*)&ldsP[r][c] = *(const float4*)(pred + (size_t)(bid * 16 + r) * D_SZ + c);
  }
  __syncthreads();
#pragma unroll
  for (int it = 0; it < 2; it++) {
    int ch = it * 256 + tid;
    int ri = ch & 15;
    int ks = (ch >> 4) & 15;
    int khh = ch >> 8;
    int kb = ks * 16 + khh * 8;
    int ln = khh * 32 + rhi + ri;
    float v[8];
#pragma unroll
    for (int j = 0; j < 8; j++) v[j] = ldsP[ri][kb + j];
    *(int2*)(predq + ((size_t)(tile * 16 + ks) * 64 + ln) * 8) = pack8_fp8(v);
  }
  int l = lane & 31;
  int half = lane >> 5;
#pragma unroll
  for (int it = 0; it < 2; it++) {
    int r = w * 4 + it * 2 + half;
    int row = bid * 16 + r;
    int lbl = label[row];
    int ltile = lbl >> 5, l5 = lbl & 31;
    int ks = l >> 1, khh = l & 1;
    int2 p8 = *(const int2*)(sigq +
        (((size_t)(ltile * 16 + ks) * 64) + khh * 32 + l5) * 8);
    float sv[8];
    unpack4_fp8(p8.x, sv);
    unpack4_fp8(p8.y, sv + 4);
    float s = 0.f;
#pragma unroll
    for (int j = 0; j < 8; j++)
      s += rt_fp8(ldsP[r][l * 8 + j]) * sv[j];
#pragma unroll
    for (int off = 16; off > 0; off >>= 1) s += __shfl_down(s, off, 32);
    if (l == 0) gt[row] = s;
  }
}

// ---- kernel 3: GEMM + hinge via MX-scaled fp8 (32x32x64, unit scales) ----
// block = 256 rows x 128 cols, 4 waves; wave = 64 rows x 128 cols.
// R2: one rowtile per outer pass -> ~80 live VGPRs (a8=32, acc=16, b8=8),
// no spill under __launch_bounds__(256,4) = 4 blocks/CU, tail-free.
// Cost: B re-read from LDS per rowtile (128 x 8B ds_reads/wave — trivial).
__global__ __launch_bounds__(256, 4) void mfma_fused_kernel(
    const char* __restrict__ predq, const char* __restrict__ sigq,
    const float* __restrict__ gt, float* __restrict__ out) {
  __shared__ char Bs[4096 * 8];   // 32 KB
  __shared__ float gtl[256];      // 1 KB: gt for this block's 256 rows
  __shared__ float red[4];
  int tid = threadIdx.x;
  int lane = tid & 63;
  int w = tid >> 6;
  int kh = lane >> 5, lm = lane & 31;
  int bid = (int)blockIdx.x;
  int i = bid >> 3;
  int rsb = (bid & 7) * 8 + (i & 7);   // row superblock 0..63 (256 rows)
  int cg = i >> 3;                     // colgroup 0..15 (128 cols)
  // per-XCD predq residency: XCD x (bid%8 round-robin) touches only rsbs
  // x*8..x*8+7 (512 KB) across ALL 16 colgroups -> L2-resident re-reads.

  // stage B tile (128 cols x 256 K fp8 = 32 KB), straight frag-major copy
#pragma unroll
  for (int s = 0; s < 8; s++) {
    int q0 = s * 256 + w * 64;         // 16 B chunk id, 0..2047
    gld_lds16(sigq + ((size_t)cg * 2048 + q0 + lane) * 16, (void*)(Bs + (size_t)q0 * 16));
  }
  // stage gt slice: 256 floats = 64 lanes x 16 B, wave 0 only
  if (w == 0)
    gld_lds16((const char*)gt + (size_t)rsb * 1024 + (size_t)lane * 16, (void*)gtl);
  __syncthreads();

  union frag8 { long l[4]; intx8 v; };
  float sum = 0.f;
#pragma unroll
  for (int rt = 0; rt < 2; rt++) {
    // A frags: full K for this rowtile as 4 x64-operands (32 VGPR)
    frag8 a8[4];
    const char* abase = predq + (size_t)(rsb * 8 + w * 2 + rt) * 8192
                              + (size_t)(kh * 1024 + lm * 8);
#pragma unroll
    for (int ks = 0; ks < 4; ks++)
#pragma unroll
      for (int g = 0; g < 4; g++)
        a8[ks].l[g] = *(const long*)(abase + ks * 2048 + g * 256);
#pragma unroll
    for (int ct = 0; ct < 4; ct++) {
      floatx16 acc = {};
      const char* bbase = Bs + ct * 8192 + kh * 1024 + lm * 8;
#pragma unroll
      for (int ks = 0; ks < 4; ks++) {
        frag8 b8;
#pragma unroll
        for (int g = 0; g < 4; g++)
          b8.l[g] = *(const long*)(bbase + ks * 2048 + g * 256);
        // unit scales: E8M0 127 -> 2^0; cbsz=0/blgp=0 -> fp8 e4m3 A and B
        acc = __builtin_amdgcn_mfma_scale_f32_32x32x64_f8f6f4(
            a8[ks].v, b8.v, acc, 0, 0, 0, 127, 0, 127);
      }
      int col = cg * 128 + ct * 32 + lm;
      float keep = (col < C_SZ) ? 1.f : 0.f;   // padded cols: s=0 but hinge!=0
#pragma unroll
      for (int reg = 0; reg < 16; reg++) {
        int rl = (reg & 3) + 8 * (reg >> 2) + 4 * kh;  // C/D row map (verified R3)
        float mg = MARGIN_F - gtl[w * 64 + rt * 32 + rl];
        sum += keep * fmaxf(acc[reg] + mg, 0.f);
      }
    }
  }
#pragma unroll
  for (int off = 32; off > 0; off >>= 1) sum += __shfl_down(sum, off, 64);
  if (lane == 0) red[w] = sum;
  __syncthreads();
  // per-block share of the label-column constant: B_SZ*MARGIN / NBLK = 16
  if (tid == 0)
    atomicAdd(out, red[0] + red[1] + red[2] + red[3]
                   - (float)B_SZ * MARGIN_F / (float)NBLK);
}

extern "C" void kernel_launch(void* const* d_in, const int* in_sizes, int n_in,
                              void* d_out, int out_size, void* d_ws, size_t ws_size,
                              hipStream_t stream) {
  const float* pred  = (const float*)d_in[0];   // (B, D) fp32
  const int*   label = (const int*)d_in[1];     // (B,)
  // d_in[2] = train_classes = arange(C), unused
  const float* sig   = (const float*)d_in[3];   // (D, C) fp32
  float* out = (float*)d_out;

  float* gt    = (float*)d_ws;                                   // 64 KB
  char*  predq = (char*)d_ws + (128 << 10);                      // 4 MB
  char*  sigq  = (char*)d_ws + (128 << 10) + (4 << 20);          // 512 KB

  sigq_kernel<<<256, 256, 0, stream>>>(sig, sigq, out);
  prep_kernel<<<1024, 256, 0, stream>>>(pred, sigq, label, predq, gt);
  mfma_fused_kernel<<<NBLK, 256, 0, stream>>>(predq, sigq, gt, out);
}

// Round 3
// 108.598 us; speedup vs baseline: 1.1452x; 1.0203x over previous
//
#include <hip/hip_runtime.h>

#define B_SZ 16384
#define D_SZ 256
#define C_SZ 2000
#define C_PAD 2048
#define MARGIN_F 1.0f
#define NBLK 1024

typedef float floatx16 __attribute__((ext_vector_type(16)));
typedef int   intx8    __attribute__((ext_vector_type(8)));

__device__ inline void gld_lds16(const void* g, void* l) {
  __builtin_amdgcn_global_load_lds(
      (const __attribute__((address_space(1))) void*)g,
      (__attribute__((address_space(3))) void*)l, 16, 0, 0);
}

// fp8 frag-major layout (verified R11-R14 prior session):
//   chunk(tile32, ks, lane) -> 8 fp8 bytes at base + ((tile*16 + ks)*64 + lane)*8
//   lane holds M[tile*32 + (lane&31)][ks*16 + (lane>>5)*8 + j], j=0..7
// k-oct o = 2*ks + (lane>>5); byte addr = tile*8192 + o*256 + (lane&31)*8.
// For mfma_scale_f32_32x32x64_f8f6f4, lane needs k = ks64*64 + (lane>>5)*32 + 0..31,
// i.e. the 4 stored k-octs o = ks64*8 + (lane>>5)*4 + g, g=0..3.
// Math verified on HW (R1/R2 absmax = 0.0). R1/R2 perf bug: the long[4]/intx8
// UNION defeated SROA -> operands lived in scratch (VGPR_Count=64, 90 MB
// scratch writes). R3: build intx8 via constant-index element inserts.

__device__ inline intx8 load_frag8(const char* base) {  // 4 x 8B, stride 256
  intx8 r;
#pragma unroll
  for (int g = 0; g < 4; g++) {
    int2 t = *(const int2*)(base + g * 256);
    r[2 * g]     = t.x;
    r[2 * g + 1] = t.y;
  }
  return r;
}

__device__ inline int2 pack8_fp8(const float* v) {
  int lo = __builtin_amdgcn_cvt_pk_fp8_f32(v[0], v[1], 0, false);
  lo = __builtin_amdgcn_cvt_pk_fp8_f32(v[2], v[3], lo, true);
  int hi = __builtin_amdgcn_cvt_pk_fp8_f32(v[4], v[5], 0, false);
  hi = __builtin_amdgcn_cvt_pk_fp8_f32(v[6], v[7], hi, true);
  return make_int2(lo, hi);
}
__device__ inline float rt_fp8(float x) {   // round-trip through fp8 e4m3
  int p = __builtin_amdgcn_cvt_pk_fp8_f32(x, x, 0, false);
  return __builtin_amdgcn_cvt_f32_fp8(p, 0);
}
__device__ inline void unpack4_fp8(int w, float* o) {  // literal selectors only
  o[0] = __builtin_amdgcn_cvt_f32_fp8(w, 0);
  o[1] = __builtin_amdgcn_cvt_f32_fp8(w, 1);
  o[2] = __builtin_amdgcn_cvt_f32_fp8(w, 2);
  o[3] = __builtin_amdgcn_cvt_f32_fp8(w, 3);
}

// ---- kernel 1: sig (D x C) fp32 -> sigq frag-major fp8; zero out[0] ----
__global__ __launch_bounds__(256) void sigq_kernel(
    const float* __restrict__ sig, char* __restrict__ sigq,
    float* __restrict__ out) {
  int t = blockIdx.x * 256 + threadIdx.x;   // 65536 chunks of 8 B
  if (t == 0) out[0] = 0.f;
  int ln = t & 63, ks = (t >> 6) & 15, ct = t >> 10;
  int col = ct * 32 + (ln & 31);
  int kb = ks * 16 + (ln >> 5) * 8;
  float v[8];
#pragma unroll
  for (int j = 0; j < 8; j++)
    v[j] = (col < C_SZ) ? sig[(size_t)(kb + j) * C_SZ + col] : 0.f;
  *(int2*)(sigq + (size_t)t * 8) = pack8_fp8(v);
}

// ---- kernel 2: prep — unchanged (verified) ----
__global__ __launch_bounds__(256) void prep_kernel(
    const float* __restrict__ pred, const char* __restrict__ sigq,
    const int* __restrict__ label, char* __restrict__ predq,
    float* __restrict__ gt) {
  __shared__ float ldsP[16][260];
  int bid = (int)blockIdx.x;
  int tid = threadIdx.x;
  int lane = tid & 63;
  int w = tid >> 6;
  int tile = bid >> 1;
  int rhi = (bid & 1) * 16;
#pragma unroll
  for (int it = 0; it < 4; it++) {
    int idx = it * 1024 + tid * 4;
    int r = idx >> 8, c = idx & 255;
    *(float4*)&ldsP[r][c] = *(const float4*)(pred + (size_t)(bid * 16 + r) * D_SZ + c);
  }
  __syncthreads();
#pragma unroll
  for (int it = 0; it < 2; it++) {
    int ch = it * 256 + tid;
    int ri = ch & 15;
    int ks = (ch >> 4) & 15;
    int khh = ch >> 8;
    int kb = ks * 16 + khh * 8;
    int ln = khh * 32 + rhi + ri;
    float v[8];
#pragma unroll
    for (int j = 0; j < 8; j++) v[j] = ldsP[ri][kb + j];
    *(int2*)(predq + ((size_t)(tile * 16 + ks) * 64 + ln) * 8) = pack8_fp8(v);
  }
  int l = lane & 31;
  int half = lane >> 5;
#pragma unroll
  for (int it = 0; it < 2; it++) {
    int r = w * 4 + it * 2 + half;
    int row = bid * 16 + r;
    int lbl = label[row];
    int ltile = lbl >> 5, l5 = lbl & 31;
    int ks = l >> 1, khh = l & 1;
    int2 p8 = *(const int2*)(sigq +
        (((size_t)(ltile * 16 + ks) * 64) + khh * 32 + l5) * 8);
    float sv[8];
    unpack4_fp8(p8.x, sv);
    unpack4_fp8(p8.y, sv + 4);
    float s = 0.f;
#pragma unroll
    for (int j = 0; j < 8; j++)
      s += rt_fp8(ldsP[r][l * 8 + j]) * sv[j];
#pragma unroll
    for (int off = 16; off > 0; off >>= 1) s += __shfl_down(s, off, 32);
    if (l == 0) gt[row] = s;
  }
}

// ---- kernel 3: GEMM + hinge via MX-scaled fp8 (32x32x64, unit scales) ----
// block = 256 rows x 128 cols, 4 waves; wave = 64 rows x 128 cols.
// One rowtile per outer pass: a8(32) + acc(16) + b8(8) + addr ~= 96 live VGPRs,
// all SROA-able (no unions, constant vector indices) -> registers, no scratch.
__global__ __launch_bounds__(256, 4) void mfma_fused_kernel(
    const char* __restrict__ predq, const char* __restrict__ sigq,
    const float* __restrict__ gt, float* __restrict__ out) {
  __shared__ char Bs[4096 * 8];   // 32 KB
  __shared__ float gtl[256];      // 1 KB: gt for this block's 256 rows
  __shared__ float red[4];
  int tid = threadIdx.x;
  int lane = tid & 63;
  int w = tid >> 6;
  int kh = lane >> 5, lm = lane & 31;
  int bid = (int)blockIdx.x;
  int i = bid >> 3;
  int rsb = (bid & 7) * 8 + (i & 7);   // row superblock 0..63 (256 rows)
  int cg = i >> 3;                     // colgroup 0..15 (128 cols)
  // per-XCD predq residency: XCD x (bid%8 round-robin) touches only rsbs
  // x*8..x*8+7 (512 KB) across ALL 16 colgroups -> L2-resident re-reads.

  // stage B tile (128 cols x 256 K fp8 = 32 KB), straight frag-major copy
#pragma unroll
  for (int s = 0; s < 8; s++) {
    int q0 = s * 256 + w * 64;         // 16 B chunk id, 0..2047
    gld_lds16(sigq + ((size_t)cg * 2048 + q0 + lane) * 16, (void*)(Bs + (size_t)q0 * 16));
  }
  // stage gt slice: 256 floats = 64 lanes x 16 B, wave 0 only
  if (w == 0)
    gld_lds16((const char*)gt + (size_t)rsb * 1024 + (size_t)lane * 16, (void*)gtl);
  __syncthreads();

  float sum = 0.f;
#pragma unroll
  for (int rt = 0; rt < 2; rt++) {
    // A frags: full K for this rowtile as 4 x64-operands (32 VGPR)
    const char* abase = predq + (size_t)(rsb * 8 + w * 2 + rt) * 8192
                              + (size_t)(kh * 1024 + lm * 8);
    intx8 a0 = load_frag8(abase);
    intx8 a1 = load_frag8(abase + 2048);
    intx8 a2 = load_frag8(abase + 4096);
    intx8 a3 = load_frag8(abase + 6144);
#pragma unroll
    for (int ct = 0; ct < 4; ct++) {
      floatx16 acc = {};
      const char* bbase = Bs + ct * 8192 + kh * 1024 + lm * 8;
      // unit scales: E8M0 127 -> 2^0; cbsz=0/blgp=0 -> fp8 e4m3 A and B
      acc = __builtin_amdgcn_mfma_scale_f32_32x32x64_f8f6f4(
          a0, load_frag8(bbase), acc, 0, 0, 0, 127, 0, 127);
      acc = __builtin_amdgcn_mfma_scale_f32_32x32x64_f8f6f4(
          a1, load_frag8(bbase + 2048), acc, 0, 0, 0, 127, 0, 127);
      acc = __builtin_amdgcn_mfma_scale_f32_32x32x64_f8f6f4(
          a2, load_frag8(bbase + 4096), acc, 0, 0, 0, 127, 0, 127);
      acc = __builtin_amdgcn_mfma_scale_f32_32x32x64_f8f6f4(
          a3, load_frag8(bbase + 6144), acc, 0, 0, 0, 127, 0, 127);
      int col = cg * 128 + ct * 32 + lm;
      float keep = (col < C_SZ) ? 1.f : 0.f;   // padded cols: s=0 but hinge!=0
#pragma unroll
      for (int reg = 0; reg < 16; reg++) {
        int rl = (reg & 3) + 8 * (reg >> 2) + 4 * kh;  // C/D row map (verified R3)
        float mg = MARGIN_F - gtl[w * 64 + rt * 32 + rl];
        sum += keep * fmaxf(acc[reg] + mg, 0.f);
      }
    }
  }
#pragma unroll
  for (int off = 32; off > 0; off >>= 1) sum += __shfl_down(sum, off, 64);
  if (lane == 0) red[w] = sum;
  __syncthreads();
  // per-block share of the label-column constant: B_SZ*MARGIN / NBLK = 16
  if (tid == 0)
    atomicAdd(out, red[0] + red[1] + red[2] + red[3]
                   - (float)B_SZ * MARGIN_F / (float)NBLK);
}

extern "C" void kernel_launch(void* const* d_in, const int* in_sizes, int n_in,
                              void* d_out, int out_size, void* d_ws, size_t ws_size,
                              hipStream_t stream) {
  const float* pred  = (const float*)d_in[0];   // (B, D) fp32
  const int*   label = (const int*)d_in[1];     // (B,)
  // d_in[2] = train_classes = arange(C), unused
  const float* sig   = (const float*)d_in[3];   // (D, C) fp32
  float* out = (float*)d_out;

  float* gt    = (float*)d_ws;                                   // 64 KB
  char*  predq = (char*)d_ws + (128 << 10);                      // 4 MB
  char*  sigq  = (char*)d_ws + (128 << 10) + (4 << 20);          // 512 KB

  sigq_kernel<<<256, 256, 0, stream>>>(sig, sigq, out);
  prep_kernel<<<1024, 256, 0, stream>>>(pred, sigq, label, predq, gt);
  mfma_fused_kernel<<<NBLK, 256, 0, stream>>>(predq, sigq, gt, out);
}

// Round 4
// 92.791 us; speedup vs baseline: 1.3402x; 1.1703x over previous
//
#include <hip/hip_runtime.h>

#define B_SZ 16384
#define D_SZ 256
#define C_SZ 2000
#define C_PAD 2048
#define MARGIN_F 1.0f
#define NBLK 1024

typedef float floatx16 __attribute__((ext_vector_type(16)));

__device__ inline void gld_lds16(const void* g, void* l) {
  __builtin_amdgcn_global_load_lds(
      (const __attribute__((address_space(1))) void*)g,
      (__attribute__((address_space(3))) void*)l, 16, 0, 0);
}

// fp8 frag-major layout (verified prior session R11-R14):
//   chunk(tile32, ks, lane) -> 8 fp8 bytes at base + ((tile*16 + ks)*64 + lane)*8
//   lane holds M[tile*32 + (lane&31)][ks*16 + (lane>>5)*8 + j], j=0..7
// R1-R3 lesson: __launch_bounds__(256,4) coerced the allocator to the 64-reg
// occupancy tier -> ~90 dwords/thread scratch spill (WRITE_SIZE 90 MB).
// R4: x16 MFMA with long operands (R0-verified codegen), NO min-waves hint,
// one rowtile per pass (~80 live regs) -> natural 4 blocks/CU.

__device__ inline int2 pack8_fp8(const float* v) {
  int lo = __builtin_amdgcn_cvt_pk_fp8_f32(v[0], v[1], 0, false);
  lo = __builtin_amdgcn_cvt_pk_fp8_f32(v[2], v[3], lo, true);
  int hi = __builtin_amdgcn_cvt_pk_fp8_f32(v[4], v[5], 0, false);
  hi = __builtin_amdgcn_cvt_pk_fp8_f32(v[6], v[7], hi, true);
  return make_int2(lo, hi);
}
__device__ inline float rt_fp8(float x) {   // round-trip through fp8 e4m3
  int p = __builtin_amdgcn_cvt_pk_fp8_f32(x, x, 0, false);
  return __builtin_amdgcn_cvt_f32_fp8(p, 0);
}
__device__ inline void unpack4_fp8(int w, float* o) {  // literal selectors only
  o[0] = __builtin_amdgcn_cvt_f32_fp8(w, 0);
  o[1] = __builtin_amdgcn_cvt_f32_fp8(w, 1);
  o[2] = __builtin_amdgcn_cvt_f32_fp8(w, 2);
  o[3] = __builtin_amdgcn_cvt_f32_fp8(w, 3);
}

// ---- kernel 1: sig (D x C) fp32 -> sigq frag-major fp8; zero out[0] ----
__global__ __launch_bounds__(256) void sigq_kernel(
    const float* __restrict__ sig, char* __restrict__ sigq,
    float* __restrict__ out) {
  int t = blockIdx.x * 256 + threadIdx.x;   // 65536 chunks of 8 B
  if (t == 0) out[0] = 0.f;
  int ln = t & 63, ks = (t >> 6) & 15, ct = t >> 10;
  int col = ct * 32 + (ln & 31);
  int kb = ks * 16 + (ln >> 5) * 8;
  float v[8];
#pragma unroll
  for (int j = 0; j < 8; j++)
    v[j] = (col < C_SZ) ? sig[(size_t)(kb + j) * C_SZ + col] : 0.f;
  *(int2*)(sigq + (size_t)t * 8) = pack8_fp8(v);
}

// ---- kernel 2: prep — unchanged (verified) ----
__global__ __launch_bounds__(256) void prep_kernel(
    const float* __restrict__ pred, const char* __restrict__ sigq,
    const int* __restrict__ label, char* __restrict__ predq,
    float* __restrict__ gt) {
  __shared__ float ldsP[16][260];
  int bid = (int)blockIdx.x;
  int tid = threadIdx.x;
  int lane = tid & 63;
  int w = tid >> 6;
  int tile = bid >> 1;
  int rhi = (bid & 1) * 16;
#pragma unroll
  for (int it = 0; it < 4; it++) {
    int idx = it * 1024 + tid * 4;
    int r = idx >> 8, c = idx & 255;
    *(float4*)&ldsP[r][c] = *(const float4*)(pred + (size_t)(bid * 16 + r) * D_SZ + c);
  }
  __syncthreads();
#pragma unroll
  for (int it = 0; it < 2; it++) {
    int ch = it * 256 + tid;
    int ri = ch & 15;
    int ks = (ch >> 4) & 15;
    int khh = ch >> 8;
    int kb = ks * 16 + khh * 8;
    int ln = khh * 32 + rhi + ri;
    float v[8];
#pragma unroll
    for (int j = 0; j < 8; j++) v[j] = ldsP[ri][kb + j];
    *(int2*)(predq + ((size_t)(tile * 16 + ks) * 64 + ln) * 8) = pack8_fp8(v);
  }
  int l = lane & 31;
  int half = lane >> 5;
#pragma unroll
  for (int it = 0; it < 2; it++) {
    int r = w * 4 + it * 2 + half;
    int row = bid * 16 + r;
    int lbl = label[row];
    int ltile = lbl >> 5, l5 = lbl & 31;
    int ks = l >> 1, khh = l & 1;
    int2 p8 = *(const int2*)(sigq +
        (((size_t)(ltile * 16 + ks) * 64) + khh * 32 + l5) * 8);
    float sv[8];
    unpack4_fp8(p8.x, sv);
    unpack4_fp8(p8.y, sv + 4);
    float s = 0.f;
#pragma unroll
    for (int j = 0; j < 8; j++)
      s += rt_fp8(ldsP[r][l * 8 + j]) * sv[j];
#pragma unroll
    for (int off = 16; off > 0; off >>= 1) s += __shfl_down(s, off, 32);
    if (l == 0) gt[row] = s;
  }
}

// ---- kernel 3: GEMM + hinge (fp8 x16 MFMA), atomic tail into out ----
// block = 256 rows x 128 cols, 4 waves; wave = 64 rows x 128 cols.
// One rowtile per pass: afr(32) + acc(16) + b(2) + addr ~= 80 live VGPRs.
// gt staged to LDS (broadcast ds_read in epilogue). NO launch-bounds min-waves.
__global__ __launch_bounds__(256) void mfma_fused_kernel(
    const char* __restrict__ predq, const char* __restrict__ sigq,
    const float* __restrict__ gt, float* __restrict__ out) {
  __shared__ char Bs[4096 * 8];   // 32 KB
  __shared__ float gtl[256];      // 1 KB: gt for this block's 256 rows
  __shared__ float red[4];
  int tid = threadIdx.x;
  int lane = tid & 63;
  int w = tid >> 6;
  int kh = lane >> 5, lm = lane & 31;
  int bid = (int)blockIdx.x;
  int i = bid >> 3;
  int rsb = (bid & 7) * 8 + (i & 7);   // row superblock 0..63 (256 rows)
  int cg = i >> 3;                     // colgroup 0..15 (128 cols)
  // per-XCD predq residency: XCD x sees rsbs x*8..x*8+7 (512 KB) across all
  // 16 colgroups -> L2-resident re-reads.

  // stage B tile (128 cols x 256 K fp8 = 32 KB), straight frag-major copy
#pragma unroll
  for (int s = 0; s < 8; s++) {
    int q0 = s * 256 + w * 64;         // 16 B chunk id, 0..2047
    gld_lds16(sigq + ((size_t)cg * 2048 + q0 + lane) * 16, (void*)(Bs + (size_t)q0 * 16));
  }
  // stage gt slice: 256 floats = 64 lanes x 16 B, wave 0 only
  if (w == 0)
    gld_lds16((const char*)gt + (size_t)rsb * 1024 + (size_t)lane * 16, (void*)gtl);

  // pass-0 A frags issued BEFORE the barrier (global, no LDS dependency)
  const char* abase0 = predq + (size_t)(rsb * 8 + w * 2) * 8192 + (size_t)lane * 8;
  long afr[16];
#pragma unroll
  for (int ks = 0; ks < 16; ks++)
    afr[ks] = *(const long*)(abase0 + (size_t)ks * 512);
  __syncthreads();

  float sum = 0.f;
#pragma unroll
  for (int rt = 0; rt < 2; rt++) {
    if (rt == 1) {
      // pass-1 A frags (L2 hits)
      const char* abase1 = abase0 + 8192;
#pragma unroll
      for (int ks = 0; ks < 16; ks++)
        afr[ks] = *(const long*)(abase1 + (size_t)ks * 512);
    }
#pragma unroll
    for (int ct = 0; ct < 4; ct++) {
      floatx16 acc = {};
      const char* bbase = Bs + (size_t)ct * 8192 + (size_t)lane * 8;
#pragma unroll
      for (int ks = 0; ks < 16; ks++) {
        long b = *(const long*)(bbase + (size_t)ks * 512);
        acc = __builtin_amdgcn_mfma_f32_32x32x16_fp8_fp8(afr[ks], b, acc, 0, 0, 0);
      }
      int col = cg * 128 + ct * 32 + lm;
      float keep = (col < C_SZ) ? 1.f : 0.f;   // padded cols: s=0 but hinge!=0
#pragma unroll
      for (int reg = 0; reg < 16; reg++) {
        int rl = (reg & 3) + 8 * (reg >> 2) + 4 * kh;  // C/D row map (verified)
        float mg = MARGIN_F - gtl[w * 64 + rt * 32 + rl];  // broadcast ds_read
        sum += keep * fmaxf(acc[reg] + mg, 0.f);
      }
    }
  }
#pragma unroll
  for (int off = 32; off > 0; off >>= 1) sum += __shfl_down(sum, off, 64);
  if (lane == 0) red[w] = sum;
  __syncthreads();
  // per-block share of the label-column constant: B_SZ*MARGIN / NBLK = 16
  if (tid == 0)
    atomicAdd(out, red[0] + red[1] + red[2] + red[3]
                   - (float)B_SZ * MARGIN_F / (float)NBLK);
}

extern "C" void kernel_launch(void* const* d_in, const int* in_sizes, int n_in,
                              void* d_out, int out_size, void* d_ws, size_t ws_size,
                              hipStream_t stream) {
  const float* pred  = (const float*)d_in[0];   // (B, D) fp32
  const int*   label = (const int*)d_in[1];     // (B,)
  // d_in[2] = train_classes = arange(C), unused
  const float* sig   = (const float*)d_in[3];   // (D, C) fp32
  float* out = (float*)d_out;

  float* gt    = (float*)d_ws;                                   // 64 KB
  char*  predq = (char*)d_ws + (128 << 10);                      // 4 MB
  char*  sigq  = (char*)d_ws + (128 << 10) + (4 << 20);          // 512 KB

  sigq_kernel<<<256, 256, 0, stream>>>(sig, sigq, out);
  prep_kernel<<<1024, 256, 0, stream>>>(pred, sigq, label, predq, gt);
  mfma_fused_kernel<<<NBLK, 256, 0, stream>>>(predq, sigq, gt, out);
}